// Round 6
// baseline (804.874 us; speedup 1.0000x reference)
//
#include <hip/hip_runtime.h>

// DynamicFilterLayer2D: out[b,c,h,w] = sum_{i,j in 3x3} xpad[b,c,h+i-1,w+j-1] * f[b,c,i*3+j,h,w]
// B=8, C=32, H=256, W=256, K=3, PAD=1. All float32.
// R5 EXPERIMENT: identical to R4 kernel but ALL nontemporal hints removed (plain loads/stores).
// Rationale: R4 (1-row, 12-deep MLP, lb(256,4)) == prior 2-row version == ~787 us, so the
// limiter is structure-independent. Both shared nt hints on 85% of traffic; harness fills
// prove 6.4 TB/s on plain stores. Testing whether the gfx950 nt path throttles streaming BW.
// Prediction: if nt-throttle, dur_us 786 -> ~560; if unchanged, nt innocent -> geometry next.

typedef float v4f __attribute__((ext_vector_type(4)));

constexpr int Bc = 8;
constexpr int Cc = 32;
constexpr int Hc = 256;
constexpr int Wc = 256;
constexpr int HW = Hc * Wc;
constexpr int W4 = Wc / 4;   // 64

__global__ __launch_bounds__(256, 4) void dyn_filter_kernel(
    const float* __restrict__ x,
    const float* __restrict__ f,
    float* __restrict__ out)
{
    int idx  = blockIdx.x * blockDim.x + threadIdx.x;
    int lane = threadIdx.x & 63;

    int w4 = idx & (W4 - 1);      // == lane (blockDim is a multiple of 64)
    int t  = idx >> 6;
    int h  = t & (Hc - 1);        // output row
    int bc = t >> 8;              // fused b*C+c plane index, [0, 256)
    int w0 = w4 << 2;

    // ---- 1) issue 3 x-row loads (h-1 .. h+1); zero for out-of-range (wave-uniform) ----
    const float* xrowbase = x + (size_t)bc * HW + w0;
    v4f r[3];
#pragma unroll
    for (int k = 0; k < 3; ++k) {
        int hy = h - 1 + k;
        if (hy >= 0 && hy < Hc)
            r[k] = *(const v4f*)(xrowbase + (size_t)hy * Wc);
        else
            r[k] = (v4f)(0.f);
    }

    // ---- 2) issue ALL 9 filter loads before any wait (max MLP) ----
    const float* fbase = f + (size_t)bc * 9 * HW + (size_t)h * Wc + w0;
    v4f fv[9];
#pragma unroll
    for (int kk = 0; kk < 9; ++kk)
        fv[kk] = *(const v4f*)(fbase + (size_t)kk * HW);

    // ---- 3) column halos via shuffle (waits only on the 3 x loads, filters in flight) ----
    float lft[3], rgt[3];
#pragma unroll
    for (int k = 0; k < 3; ++k) {
        lft[k] = __shfl_up(r[k].w, 1);
        rgt[k] = __shfl_down(r[k].x, 1);
        if (lane == 0)  lft[k] = 0.f;   // zero pad at w = -1
        if (lane == 63) rgt[k] = 0.f;   // zero pad at w = 256
    }

    // ---- 4) FMA drain, consuming filters in issue order ----
    v4f acc = (v4f)(0.f);
#pragma unroll
    for (int di = 0; di < 3; ++di) {
        v4f   xa = r[di];
        float la = lft[di];
        float ra = rgt[di];
#pragma unroll
        for (int dj = 0; dj < 3; ++dj) {
            v4f wa;
            if (dj == 0) {        // window cols w-1..w+2
                wa = (v4f){la,   xa.x, xa.y, xa.z};
            } else if (dj == 1) { // centered
                wa = xa;
            } else {              // window cols w+1..w+4
                wa = (v4f){xa.y, xa.z, xa.w, ra};
            }
            acc += wa * fv[di * 3 + dj];
        }
    }

    float* op = out + (size_t)bc * HW + (size_t)h * Wc + w0;
    *(v4f*)op = acc;
}

extern "C" void kernel_launch(void* const* d_in, const int* in_sizes, int n_in,
                              void* d_out, int out_size, void* d_ws, size_t ws_size,
                              hipStream_t stream) {
    const float* x = (const float*)d_in[0];
    const float* f = (const float*)d_in[1];
    float* out = (float*)d_out;

    int total = Bc * Cc * Hc * W4;           // 4,194,304 threads
    int block = 256;
    int grid  = (total + block - 1) / block; // 16384 blocks
    dyn_filter_kernel<<<grid, block, 0, stream>>>(x, f, out);
}

// Round 7
// 794.883 us; speedup vs baseline: 1.0126x; 1.0126x over previous
//
#include <hip/hip_runtime.h>

// DynamicFilterLayer2D: out[b,c,h,w] = sum_{i,j in 3x3} xpad[b,c,h+i-1,w+j-1] * f[b,c,i*3+j,h,w]
// B=8, C=32, H=256, W=256, K=3, PAD=1. All float32. ~805 MB traffic -> roofline ~128 us.
// R6 EXPERIMENT: persistent grid-stride (2048 blocks x 8 tiles/thread) with the R4 body (nt
// restored = best-measured config). Rationale: R0/R4/R5 (one-shot waves, wildly different
// occupancy/MLP/burst/cache-policy) are all ~787-805 us (~2 TB/s kernel), while harness fills
// stream 6.4 TB/s at 10% occupancy with grid-stride loops. Last unfalsified structural
// difference: one-shot wave lifecycle + 16384-WG dispatch churn vs persistent streaming waves.
// Prediction: if lifecycle/dispatch-bound, dur 787 -> ~500-560; if unchanged, plateau reached.

typedef float v4f __attribute__((ext_vector_type(4)));

constexpr int Bc = 8;
constexpr int Cc = 32;
constexpr int Hc = 256;
constexpr int Wc = 256;
constexpr int HW = Hc * Wc;
constexpr int W4 = Wc / 4;                 // 64 lanes worth of v4f per row
constexpr int TOTAL = Bc * Cc * Hc * W4;   // 4,194,304 work items
constexpr int NBLK  = 2048;                // 8 blocks/CU on 256 CUs
constexpr int BLKSZ = 256;
constexpr int STRIDE = NBLK * BLKSZ;       // 524,288 (multiple of 64: lane<->w4 invariant)

__global__ __launch_bounds__(BLKSZ, 4) void dyn_filter_kernel(
    const float* __restrict__ x,
    const float* __restrict__ f,
    float* __restrict__ out)
{
    int tid0 = blockIdx.x * BLKSZ + threadIdx.x;
    int lane = threadIdx.x & 63;

    for (int idx = tid0; idx < TOTAL; idx += STRIDE) {   // exactly 8 iterations, no tail
        int w4 = idx & (W4 - 1);      // == lane
        int t  = idx >> 6;
        int h  = t & (Hc - 1);        // output row
        int bc = t >> 8;              // fused b*C+c plane index
        int w0 = w4 << 2;

        // ---- 1) issue 3 x-row loads (h-1 .. h+1); zero for out-of-range (wave-uniform) ----
        const float* xrowbase = x + (size_t)bc * HW + w0;
        v4f r[3];
#pragma unroll
        for (int k = 0; k < 3; ++k) {
            int hy = h - 1 + k;
            if (hy >= 0 && hy < Hc)
                r[k] = *(const v4f*)(xrowbase + (size_t)hy * Wc);
            else
                r[k] = (v4f)(0.f);
        }

        // ---- 2) issue ALL 9 filter loads before any wait (12 VMEM in flight) ----
        const float* fbase = f + (size_t)bc * 9 * HW + (size_t)h * Wc + w0;
        v4f fv[9];
#pragma unroll
        for (int kk = 0; kk < 9; ++kk)
            fv[kk] = __builtin_nontemporal_load((const v4f*)(fbase + (size_t)kk * HW));

        // ---- 3) column halos via shuffle (waits only on x loads; filters still flying) ----
        float lft[3], rgt[3];
#pragma unroll
        for (int k = 0; k < 3; ++k) {
            lft[k] = __shfl_up(r[k].w, 1);
            rgt[k] = __shfl_down(r[k].x, 1);
            if (lane == 0)  lft[k] = 0.f;   // zero pad at w = -1
            if (lane == 63) rgt[k] = 0.f;   // zero pad at w = 256
        }

        // ---- 4) FMA drain ----
        v4f acc = (v4f)(0.f);
#pragma unroll
        for (int di = 0; di < 3; ++di) {
            v4f   xa = r[di];
            float la = lft[di];
            float ra = rgt[di];
#pragma unroll
            for (int dj = 0; dj < 3; ++dj) {
                v4f wa;
                if (dj == 0) {        // window cols w-1..w+2
                    wa = (v4f){la,   xa.x, xa.y, xa.z};
                } else if (dj == 1) { // centered
                    wa = xa;
                } else {              // window cols w+1..w+4
                    wa = (v4f){xa.y, xa.z, xa.w, ra};
                }
                acc += wa * fv[di * 3 + dj];
            }
        }

        float* op = out + (size_t)bc * HW + (size_t)h * Wc + w0;
        __builtin_nontemporal_store(acc, (v4f*)op);
    }
}

extern "C" void kernel_launch(void* const* d_in, const int* in_sizes, int n_in,
                              void* d_out, int out_size, void* d_ws, size_t ws_size,
                              hipStream_t stream) {
    const float* x = (const float*)d_in[0];
    const float* f = (const float*)d_in[1];
    float* out = (float*)d_out;

    dyn_filter_kernel<<<NBLK, BLKSZ, 0, stream>>>(x, f, out);
}